// Round 23
// baseline (311.618 us; speedup 1.0000x reference)
//
#include <hip/hip_runtime.h>
#include <hip/hip_bf16.h>
#include <stdint.h>

#define TSEQ 4096
#define DM   1024
#define NH   16
#define HD   64
#define NQKV 3072

typedef unsigned short u16;
typedef unsigned int   u32;
typedef __attribute__((ext_vector_type(8)))  short bf16x8;
typedef __attribute__((ext_vector_type(4)))  float f32x4;
typedef __attribute__((ext_vector_type(16))) float f32x16;
typedef __attribute__((ext_vector_type(4)))  int   i32x4;

static __device__ __forceinline__ u16 f2bf(float f) {
  u32 u = __float_as_uint(f);
  u32 r = (u + 0x7FFFu + ((u >> 16) & 1u)) >> 16;   // RNE
  return (u16)r;
}
static __device__ __forceinline__ float bf2f(u16 u) {
  return __uint_as_float(((u32)u) << 16);
}
static __device__ __forceinline__ u32 cvt_pk_bf16(float lo, float hi) {
  u32 r;
  asm("v_cvt_pk_bf16_f32 %0, %1, %2" : "=v"(r) : "v"(lo), "v"(hi));
  return r;
}
static __device__ __forceinline__ float fexp2(float x) {   // guaranteed v_exp_f32
  float r;
  asm("v_exp_f32 %0, %1" : "=v"(r) : "v"(x));
  return r;
}

#define GLL16(g, l) __builtin_amdgcn_global_load_lds( \
    (const __attribute__((address_space(1))) u32*)(g), \
    (__attribute__((address_space(3))) u32*)(l), 16, 0, 0)

// ---------------- fused cast fp32 -> bf16 for x, W_qkv, W_proj --------------
#define N4X  (TSEQ * DM / 4)
#define N4Q  (NQKV * DM / 4)
#define N4P  (DM * DM / 4)
__global__ void cast3_kernel(const float* __restrict__ x, u16* __restrict__ xo,
                             const float* __restrict__ wq, u16* __restrict__ wqo,
                             const float* __restrict__ wp, u16* __restrict__ wpo) {
  int i = blockIdx.x * 256 + threadIdx.x;
  const float* in; u16* out; int k;
  if (i < N4X)            { in = x;  out = xo;  k = i; }
  else if (i < N4X + N4Q) { in = wq; out = wqo; k = i - N4X; }
  else if (i < N4X + N4Q + N4P) { in = wp; out = wpo; k = i - N4X - N4Q; }
  else return;
  float4 v = ((const float4*)in)[k];
  ushort4 o;
  o.x = f2bf(v.x); o.y = f2bf(v.y); o.z = f2bf(v.z); o.w = f2bf(v.w);
  ((ushort4*)out)[k] = o;
}

// ---------------- RoPE sin/cos table [T][32] ----------------
__global__ void rope_table(float* __restrict__ sT, float* __restrict__ cT) {
  int i = blockIdx.x * 256 + threadIdx.x;   // t*32 + j
  int t = i >> 5, j = i & 31;
  float inv = exp2f((float)j * (-13.287712379549449f / 32.0f)); // 10000^(-j/32)
  float ang = (float)t * inv;
  sT[i] = sinf(ang);
  cT[i] = cosf(ang);
}

// ---------------- gemm1 + fused RoPE/head-split epilogue ---------------------
// C = x[4096,1024] * Wqkv[3072,1024]^T. Tile 128x128, 8 waves (4x2), 512 thr.
// T2 XOR-swizzle on LDS tiles via pre-swizzled GLL source; 2D-chunked XCD map.
__global__ __launch_bounds__(512) void gemm_qkv(const u16* __restrict__ A,
                                                const u16* __restrict__ B,
                                                const float* __restrict__ sT,
                                                const float* __restrict__ cT,
                                                u16* __restrict__ Qo,
                                                u16* __restrict__ Ko,
                                                u16* __restrict__ Vo)
{
  const int K = DM;
  __shared__ __align__(16) u16 As[2][128 * 32];
  __shared__ __align__(16) u16 Bs[2][128 * 32];
  const int tid  = threadIdx.x;
  const int wave = tid >> 6, lane = tid & 63;
  const int l15  = lane & 15, lh = lane >> 4;
  const int wr   = wave >> 1, wc = wave & 1;          // 4x2: 32-row x 64-col waves

  int lin = blockIdx.y * gridDim.x + blockIdx.x;      // 0..767
  const int xcd = lin & 7, idx = lin >> 3;            // 96 tiles per XCD
  const size_t bm = (size_t)((xcd & 3) * 8 + idx / 12);    // 0..31
  const size_t bn = (size_t)((xcd >> 2) * 12 + idx % 12);  // 0..23

  f32x4 acc[2][4] = {};

  const u16* Ab = A + bm * 128 * (size_t)K;
  const u16* Bb = B + bn * 128 * (size_t)K;

  const int ea = tid * 8, ra = ea >> 5;
  const int cs = (((tid & 3) ^ (ra & 3)) << 3);       // pre-swizzled source col
  const int xo = ((lh ^ (l15 & 3)) << 3);             // read-side swizzle

  // prologue: stage k=0 into buf 0
  GLL16(Ab + (size_t)ra * K + cs, &As[0][ea]);
  GLL16(Bb + (size_t)ra * K + cs, &Bs[0][ea]);
  asm volatile("s_waitcnt vmcnt(0)" ::: "memory");
  __syncthreads();

  int cur = 0;
  for (int k0 = 0; k0 < K; k0 += 32, cur ^= 1) {
    if (k0 + 32 < K) {
      const int kn = k0 + 32;
      GLL16(Ab + (size_t)ra * K + kn + cs, &As[cur ^ 1][ea]);
      GLL16(Bb + (size_t)ra * K + kn + cs, &Bs[cur ^ 1][ea]);
    }

    bf16x8 af[2], bfr[4];
#pragma unroll
    for (int m = 0; m < 2; ++m)
      af[m] = *(const bf16x8*)(&As[cur][(wr * 32 + m * 16 + l15) * 32 + xo]);
#pragma unroll
    for (int n = 0; n < 4; ++n)
      bfr[n] = *(const bf16x8*)(&Bs[cur][(wc * 64 + n * 16 + l15) * 32 + xo]);
    __builtin_amdgcn_s_setprio(1);
#pragma unroll
    for (int m = 0; m < 2; ++m)
#pragma unroll
      for (int n = 0; n < 4; ++n)
        acc[m][n] = __builtin_amdgcn_mfma_f32_16x16x32_bf16(af[m], bfr[n], acc[m][n], 0, 0, 0);
    __builtin_amdgcn_s_setprio(0);

    asm volatile("s_waitcnt vmcnt(0)" ::: "memory");
    __syncthreads();
  }

  // ---- fused epilogue: RoPE + scatter into fragment layouts ----
  const float QSC = 0.125f * 1.4426950408889634f;    // 1/sqrt(64) * log2(e)
  const int gcb = (int)(bn * 128) + wc * 64;         // wave col base (64-aligned)
  const int rg  = gcb >> 10;                         // 0=Q, 1=K, 2=V
  const int hh2 = (gcb >> 6) & 15;                   // head
  const size_t hb = (size_t)hh2 * 128;

  if (rg < 2) {
    u16* dst = rg ? Ko : Qo;
    const float sc = rg ? 1.f : QSC;
#pragma unroll
    for (int m = 0; m < 2; ++m)
#pragma unroll
      for (int r = 0; r < 4; ++r) {
        int t = (int)(bm * 128) + wr * 32 + m * 16 + lh * 4 + r;
        size_t tb = (hb + (t >> 5)) * 2048 + (size_t)(t & 31) * 8;
#pragma unroll
        for (int n = 0; n < 2; ++n) {
          int d  = n * 16 + l15;                      // < 32
          int d2 = d + 32;
          float s = sT[t * 32 + d], c = cT[t * 32 + d];
          float v1 = acc[m][n][r], v2 = acc[m][n + 2][r];
          dst[tb + (d  >> 4) * 512 + ((d  >> 3) & 1) * 256 + (d  & 7)] =
              f2bf((v1 * c - v2 * s) * sc);
          dst[tb + (d2 >> 4) * 512 + ((d2 >> 3) & 1) * 256 + (d2 & 7)] =
              f2bf((v2 * c + v1 * s) * sc);
        }
      }
  } else {
#pragma unroll
    for (int m = 0; m < 2; ++m)
#pragma unroll
      for (int r = 0; r < 4; ++r) {
        int t = (int)(bm * 128) + wr * 32 + m * 16 + lh * 4 + r;
        size_t tb = (hb + (t >> 5)) * 2048 + (size_t)((t >> 4) & 1) * 512 +
                    ((t >> 3) & 1) * 256 + (t & 7);
#pragma unroll
        for (int n = 0; n < 4; ++n) {
          int d = n * 16 + l15;
          Vo[tb + (size_t)(d >> 5) * 1024 + (size_t)(d & 31) * 8] = f2bf(acc[m][n][r]);
        }
      }
  }
}

// ---------------- GEMM C[M,N] = A[M,K]*B[N,K]^T (proj, fp32 out) ------------
// Tile 64x64, 4 waves (2x2), grid 1024 blocks; T2 XOR-swizzle as in gemm_qkv.
__global__ __launch_bounds__(256) void gemm_proj(const u16* __restrict__ A,
                                                 const u16* __restrict__ B,
                                                 float* __restrict__ Cout,
                                                 int M, int N, int K)
{
  __shared__ __align__(16) u16 As[2][64 * 32];
  __shared__ __align__(16) u16 Bs[2][64 * 32];
  const int tid  = threadIdx.x;
  const int wave = tid >> 6, lane = tid & 63;
  const int l15  = lane & 15, lh = lane >> 4;
  const int wr   = wave >> 1, wc = wave & 1;

  int lin = blockIdx.y * gridDim.x + blockIdx.x;      // 0..1023
  const int xcd = lin & 7, idx = lin >> 3;            // 128 tiles per XCD
  const size_t bm = (size_t)((xcd & 3) * 16 + idx / 8);   // 0..63
  const size_t bn = (size_t)((xcd >> 2) * 8 + idx % 8);   // 0..15

  f32x4 acc[2][2] = {};

  const u16* Ab = A + bm * 64 * (size_t)K;
  const u16* Bb = B + bn * 64 * (size_t)K;

  const int ea = wave * 512 + lane * 8, ra = ea >> 5;
  const int cs = (((lane & 3) ^ (ra & 3)) << 3);      // pre-swizzled source col
  const int xo = ((lh ^ (l15 & 3)) << 3);             // read-side swizzle

  GLL16(Ab + (size_t)ra * K + cs, &As[0][ea]);
  GLL16(Bb + (size_t)ra * K + cs, &Bs[0][ea]);
  asm volatile("s_waitcnt vmcnt(0)" ::: "memory");
  __syncthreads();

  int cur = 0;
  for (int k0 = 0; k0 < K; k0 += 32, cur ^= 1) {
    if (k0 + 32 < K) {
      const int kn = k0 + 32;
      GLL16(Ab + (size_t)ra * K + kn + cs, &As[cur ^ 1][ea]);
      GLL16(Bb + (size_t)ra * K + kn + cs, &Bs[cur ^ 1][ea]);
    }

    bf16x8 af[2], bfr[2];
#pragma unroll
    for (int m = 0; m < 2; ++m)
      af[m] = *(const bf16x8*)(&As[cur][(wr * 32 + m * 16 + l15) * 32 + xo]);
#pragma unroll
    for (int n = 0; n < 2; ++n)
      bfr[n] = *(const bf16x8*)(&Bs[cur][(wc * 32 + n * 16 + l15) * 32 + xo]);
    __builtin_amdgcn_s_setprio(1);
#pragma unroll
    for (int m = 0; m < 2; ++m)
#pragma unroll
      for (int n = 0; n < 2; ++n)
        acc[m][n] = __builtin_amdgcn_mfma_f32_16x16x32_bf16(af[m], bfr[n], acc[m][n], 0, 0, 0);
    __builtin_amdgcn_s_setprio(0);

    asm volatile("s_waitcnt vmcnt(0)" ::: "memory");
    __syncthreads();
  }

#pragma unroll
  for (int m = 0; m < 2; ++m)
#pragma unroll
    for (int n = 0; n < 2; ++n)
#pragma unroll
      for (int r = 0; r < 4; ++r) {
        size_t row = bm * 64 + wr * 32 + m * 16 + lh * 4 + r;
        size_t col = bn * 64 + wc * 32 + n * 16 + l15;
        Cout[row * N + col] = acc[m][n][r];
      }
}

// ---------------- causal flash attention: barrier-free + reg ping-pong ------
// grid 16h x 32qt x 4g = 2048 blocks x 256 thr, big-qt first. K/V fragments
// global->reg with PING-PONG PREFETCH: kt+1's loads issue BEFORE kt's QK
// chain, so they hide under kt's QK+softmax+PV (~600-800 cyc). No LDS staging,
// no barriers; waves fully independent. LDS only for epilogue bounce.
#define FLOAD(KF, VF, ktv)                                                \
  do {                                                                    \
    const u16* kb_ = kg + (size_t)(ktv) * 2048;                           \
    const u16* vb_ = vg + (size_t)(ktv) * 2048;                           \
    _Pragma("unroll")                                                     \
    for (int kc = 0; kc < 4; ++kc)                                        \
      KF[kc] = *(const bf16x8*)(kb_ + kc * 512 + lb);                     \
    _Pragma("unroll")                                                     \
    for (int s2 = 0; s2 < 2; ++s2) {                                      \
      VF[s2]     = *(const bf16x8*)(vb_ + (0 * 2 + s2) * 512 + lb);       \
      VF[2 + s2] = *(const bf16x8*)(vb_ + (1 * 2 + s2) * 512 + lb);       \
    }                                                                     \
  } while (0)

#define FSTEP(KF, VF, ktv)                                                \
  do {                                                                    \
    const int kv0 = (ktv) * 32;                                           \
    const float mz = ((ktv) == kt0) ? 0.f : -mrun;                        \
    f32x16 s0;                                                            \
    __builtin_amdgcn_s_setprio(1);                                        \
    {                                                                     \
      f32x16 z;                                                           \
      _Pragma("unroll")                                                   \
      for (int i2 = 0; i2 < 16; ++i2) z[i2] = mz;                         \
      s0 = __builtin_amdgcn_mfma_f32_32x32x16_bf16(KF[0], qf[0], z, 0, 0, 0); \
    }                                                                     \
    _Pragma("unroll")                                                     \
    for (int kc = 1; kc < 4; ++kc)                                        \
      s0 = __builtin_amdgcn_mfma_f32_32x32x16_bf16(KF[kc], qf[kc], s0, 0, 0, 0); \
    __builtin_amdgcn_s_setprio(0);                                        \
    if (kv0 + 31 > qw0) {                                                 \
      _Pragma("unroll")                                                   \
      for (int r = 0; r < 16; ++r) {                                      \
        int kvr = kv0 + (r & 3) + 8 * (r >> 2) + 4 * hh;                  \
        if (kvr > qgl) s0[r] = -3.0e38f;                                  \
      }                                                                   \
    }                                                                     \
    if ((ktv) == kt0) {                                                   \
      float tm = -3.0e38f;                                                \
      _Pragma("unroll")                                                   \
      for (int r = 0; r < 16; ++r) tm = fmaxf(tm, s0[r]);                 \
      tm = fmaxf(tm, __shfl_xor(tm, 32));                                 \
      mrun = tm;                                                          \
      _Pragma("unroll")                                                   \
      for (int r = 0; r < 16; ++r) s0[r] -= mrun;                         \
    }                                                                     \
    float rs = 0.f;                                                       \
    _Pragma("unroll")                                                     \
    for (int r = 0; r < 16; ++r) {                                        \
      s0[r] = fexp2(s0[r]);                                               \
      rs += s0[r];                                                        \
    }                                                                     \
    lrunp += rs;                                                          \
    bf16x8 pf[2];                                                         \
    _Pragma("unroll")                                                     \
    for (int kc = 0; kc < 2; ++kc) {                                      \
      const int e = 8 * kc;                                               \
      u32 Xa = cvt_pk_bf16(s0[e + 0], s0[e + 1]);                         \
      u32 Xb = cvt_pk_bf16(s0[e + 2], s0[e + 3]);                         \
      u32 Ya = cvt_pk_bf16(s0[e + 4], s0[e + 5]);                         \
      u32 Yb = cvt_pk_bf16(s0[e + 6], s0[e + 7]);                         \
      asm volatile("v_permlane32_swap_b32 %0, %1" : "+v"(Xa), "+v"(Ya));  \
      asm volatile("v_permlane32_swap_b32 %0, %1" : "+v"(Xb), "+v"(Yb));  \
      union { u32 u[4]; bf16x8 v; } pu;                                   \
      pu.u[0] = Xa; pu.u[1] = Xb; pu.u[2] = Ya; pu.u[3] = Yb;             \
      pf[kc] = pu.v;                                                      \
    }                                                                     \
    __builtin_amdgcn_s_setprio(1);                                        \
    _Pragma("unroll")                                                     \
    for (int s2 = 0; s2 < 2; ++s2) {                                      \
      oacc0 = __builtin_amdgcn_mfma_f32_32x32x16_bf16(VF[s2],     pf[s2], oacc0, 0, 0, 0); \
      oacc1 = __builtin_amdgcn_mfma_f32_32x32x16_bf16(VF[2 + s2], pf[s2], oacc1, 0, 0, 0); \
    }                                                                     \
    __builtin_amdgcn_s_setprio(0);                                        \
  } while (0)

__global__ __launch_bounds__(256, 4) void fattn(const u16* __restrict__ Qf,
                                                const u16* __restrict__ Kf,
                                                const u16* __restrict__ Vf,
                                                u16* __restrict__ Op0,
                                                u16* __restrict__ Op123,
                                                float2* __restrict__ lmb)
{
  __shared__ __align__(16) u16 smem[8192];   // epilogue bounce only (4KB/wave)

  const int bid = blockIdx.x;
  const int h   = bid & (NH - 1);
  const int g   = (bid >> 4) & 3;            // kv group
  const int qt  = 31 - (bid >> 6);           // big q-tiles dispatched first
  const int tid = threadIdx.x;
  const int wave = tid >> 6, lane = tid & 63;
  const int l31 = lane & 31, hh = lane >> 5;
  const int lb  = lane * 8;                  // linear fragment offset (elems)

  const size_t hbase = (size_t)h * (TSEQ * HD);
  const u16* kg = Kf + hbase;
  const u16* vg = Vf + hbase;
  u16* const Og = g ? (Op123 + (size_t)(g - 1) * (TSEQ * DM)) : Op0;

  const int q0  = qt * 128;
  const int per = qt + 1;                    // 32-kv tiles per group (exact)
  const int kt0 = g * per, kt1 = kt0 + per;
  const int qw0 = q0 + wave * 32;            // this wave's first q row
  const int qgl = qw0 + l31;                 // this lane's q row (global)

  f32x16 oacc0 = {}, oacc1 = {};
  float mrun = 0.f, lrunp = 0.f;             // LANE-PARTIAL l

  // Q fragments (B-operand), 4 k-chunks of 16 d
  bf16x8 qf[4];
  {
    const u16* qp = Qf + hbase + (size_t)(qt * 4 + wave) * 2048;
#pragma unroll
    for (int kc = 0; kc < 4; ++kc)
      qf[kc] = *(const bf16x8*)(qp + kc * 512 + lb);
  }

  bf16x8 kA[4], vA[4], kB[4], vB[4];
  FLOAD(kA, vA, kt0);

  int kt = kt0;
  for (;;) {
    {   // step uses set A, prefetches set B
      if (kt + 1 < kt1) FLOAD(kB, vB, kt + 1);
      FSTEP(kA, vA, kt);
    }
    if (++kt == kt1) break;
    {   // step uses set B, prefetches set A
      if (kt + 1 < kt1) FLOAD(kA, vA, kt + 1);
      FSTEP(kB, vB, kt);
    }
    if (++kt == kt1) break;
  }

  // ---- epilogue: reduce lane-partial l, normalize, LDS bounce, store -----
  {
    float lr = lrunp + __shfl_xor(lrunp, 32);
    float inv = 1.f / lr;
    u16* scr = smem + wave * 2048;           // wave-private 4KB
#pragma unroll
    for (int dt = 0; dt < 2; ++dt)
#pragma unroll
      for (int rq = 0; rq < 4; ++rq) {
        float v0 = (dt ? oacc1[4 * rq + 0] : oacc0[4 * rq + 0]) * inv;
        float v1 = (dt ? oacc1[4 * rq + 1] : oacc0[4 * rq + 1]) * inv;
        float v2 = (dt ? oacc1[4 * rq + 2] : oacc0[4 * rq + 2]) * inv;
        float v3 = (dt ? oacc1[4 * rq + 3] : oacc0[4 * rq + 3]) * inv;
        uint2 wv;
        wv.x = cvt_pk_bf16(v0, v1);
        wv.y = cvt_pk_bf16(v2, v3);
        int g2 = 4 * dt + rq;
        *(uint2*)(scr + l31 * 64 + ((g2 ^ (l31 & 7)) * 8) + 4 * hh) = wv;
      }
    asm volatile("s_waitcnt lgkmcnt(0)" ::: "memory");
    __builtin_amdgcn_sched_barrier(0);
    const int q  = lane >> 1;                // 32 rows x 2 d-halves
    const int dh = lane & 1;
#pragma unroll
    for (int c2 = 0; c2 < 4; ++c2) {
      int gg = dh * 4 + c2;
      i32x4 v = *(const i32x4*)(scr + q * 64 + ((gg ^ (q & 7)) * 8));
      *(i32x4*)(Og + (size_t)(qw0 + q) * DM + h * HD + dh * 32 + c2 * 8) = v;
    }
    if (hh == 0)                             // per-q stats (m log2-domain, l)
      lmb[((size_t)g * NH + h) * TSEQ + qgl] = make_float2(mrun, lr);
  }
}

// ---------------- merge the four kv-group partials ----------------
// O[q][h*64+d] = sum_g a_g * O_g,  a_g = 2^(m_g - m) * l_g / sum
__global__ void merge_o(const u16* __restrict__ Op0, const u16* __restrict__ Op123,
                        const float2* __restrict__ lmb, u16* __restrict__ Ob) {
  int i = blockIdx.x * 256 + threadIdx.x;    // [0, TSEQ*DM/8)
  int q  = i >> 7;
  int c8 = (i & 127) * 8;
  int h  = c8 >> 6;
  float2 s0 = lmb[(size_t)h * TSEQ + q];
  float2 s1 = lmb[((size_t)NH + h) * TSEQ + q];
  float2 s2 = lmb[((size_t)2 * NH + h) * TSEQ + q];
  float2 s3 = lmb[((size_t)3 * NH + h) * TSEQ + q];
  float m  = fmaxf(fmaxf(s0.x, s1.x), fmaxf(s2.x, s3.x));
  float w0 = fexp2(s0.x - m) * s0.y;
  float w1 = fexp2(s1.x - m) * s1.y;
  float w2 = fexp2(s2.x - m) * s2.y;
  float w3 = fexp2(s3.x - m) * s3.y;
  float inv = 1.f / (w0 + w1 + w2 + w3);
  float a0 = w0 * inv, a1 = w1 * inv, a2 = w2 * inv, a3 = w3 * inv;
  size_t off = (size_t)q * DM + c8;
  i32x4 u0 = *(const i32x4*)(Op0 + off);
  i32x4 u1 = *(const i32x4*)(Op123 + off);
  i32x4 u2 = *(const i32x4*)(Op123 + (size_t)(TSEQ * DM) + off);
  i32x4 u3 = *(const i32x4*)(Op123 + 2 * (size_t)(TSEQ * DM) + off);
  const u16* p0 = (const u16*)&u0;
  const u16* p1 = (const u16*)&u1;
  const u16* p2 = (const u16*)&u2;
  const u16* p3 = (const u16*)&u3;
  union { u16 o[8]; i32x4 v; } r;
#pragma unroll
  for (int e = 0; e < 8; ++e)
    r.o[e] = f2bf(a0 * bf2f(p0[e]) + a1 * bf2f(p1[e]) +
                  a2 * bf2f(p2[e]) + a3 * bf2f(p3[e]));
  *(i32x4*)(Ob + off) = r.v;
}

extern "C" void kernel_launch(void* const* d_in, const int* in_sizes, int n_in,
                              void* d_out, int out_size, void* d_ws, size_t ws_size,
                              hipStream_t stream)
{
  const float* x     = (const float*)d_in[0];
  const float* wqkv  = (const float*)d_in[1];
  const float* wproj = (const float*)d_in[2];
  float* out = (float*)d_out;

  char* ws = (char*)d_ws;
  size_t off = 0;
  u16* xb   = (u16*)(ws + off); off += (size_t)TSEQ * DM * 2;
  u16* wqb  = (u16*)(ws + off); off += (size_t)NQKV * DM * 2;
  u16* wpb  = (u16*)(ws + off); off += (size_t)DM * DM * 2;
  u16* qkvb = (u16*)(ws + off); off += (size_t)TSEQ * NQKV * 2;   // scratch (partials)
  u16* Qb   = (u16*)(ws + off); off += (size_t)NH * TSEQ * HD * 2;
  u16* Kb   = (u16*)(ws + off); off += (size_t)NH * TSEQ * HD * 2;
  u16* Vb   = (u16*)(ws + off); off += (size_t)NH * TSEQ * HD * 2;
  u16* Ob   = (u16*)(ws + off); off += (size_t)TSEQ * DM * 2;
  float* sT = (float*)(ws + off); off += (size_t)TSEQ * 32 * 4;
  float* cT = (float*)(ws + off); off += (size_t)TSEQ * 32 * 4;

  // kv-split partials: g0 writes Ob directly; g1-3 alias qkvb (24MB scratch);
  // stats alias wqb (dead after gemm_qkv).
  u16*    Op123 = qkvb;
  float2* lmb   = (float2*)wqb;

  const int ncast = N4X + N4Q + N4P;
  cast3_kernel<<<(ncast + 255) / 256, 256, 0, stream>>>(x, xb, wqkv, wqb, wproj, wpb);
  rope_table<<<(TSEQ * 32) / 256, 256, 0, stream>>>(sT, cT);

  gemm_qkv<<<dim3(NQKV / 128, TSEQ / 128), 512, 0, stream>>>(xb, wqb, sT, cT, Qb, Kb, Vb);

  fattn<<<NH * 32 * 4, 256, 0, stream>>>(Qb, Kb, Vb, Ob, Op123, lmb);

  merge_o<<<(TSEQ * DM / 8) / 256, 256, 0, stream>>>(Ob, Op123, lmb, Ob);

  gemm_proj<<<dim3(DM / 64, TSEQ / 64), 256, 0, stream>>>(Ob, wpb, out, TSEQ, DM, DM);
}

// Round 24
// 123.375 us; speedup vs baseline: 2.5258x; 2.5258x over previous
//
#include <hip/hip_runtime.h>
#include <hip/hip_bf16.h>
#include <stdint.h>

#define TSEQ 4096
#define DM   1024
#define NH   16
#define HD   64
#define NQKV 3072

typedef unsigned short u16;
typedef unsigned int   u32;
typedef __attribute__((ext_vector_type(8)))  short bf16x8;
typedef __attribute__((ext_vector_type(4)))  float f32x4;
typedef __attribute__((ext_vector_type(16))) float f32x16;
typedef __attribute__((ext_vector_type(4)))  int   i32x4;

static __device__ __forceinline__ u16 f2bf(float f) {
  u32 u = __float_as_uint(f);
  u32 r = (u + 0x7FFFu + ((u >> 16) & 1u)) >> 16;   // RNE
  return (u16)r;
}
static __device__ __forceinline__ float bf2f(u16 u) {
  return __uint_as_float(((u32)u) << 16);
}
static __device__ __forceinline__ u32 cvt_pk_bf16(float lo, float hi) {
  u32 r;
  asm("v_cvt_pk_bf16_f32 %0, %1, %2" : "=v"(r) : "v"(lo), "v"(hi));
  return r;
}
static __device__ __forceinline__ float fexp2(float x) {   // guaranteed v_exp_f32
  float r;
  asm("v_exp_f32 %0, %1" : "=v"(r) : "v"(x));
  return r;
}

#define GLL16(g, l) __builtin_amdgcn_global_load_lds( \
    (const __attribute__((address_space(1))) u32*)(g), \
    (__attribute__((address_space(3))) u32*)(l), 16, 0, 0)

// ---------------- fused cast fp32 -> bf16 for x, W_qkv, W_proj --------------
#define N4X  (TSEQ * DM / 4)
#define N4Q  (NQKV * DM / 4)
#define N4P  (DM * DM / 4)
__global__ void cast3_kernel(const float* __restrict__ x, u16* __restrict__ xo,
                             const float* __restrict__ wq, u16* __restrict__ wqo,
                             const float* __restrict__ wp, u16* __restrict__ wpo) {
  int i = blockIdx.x * 256 + threadIdx.x;
  const float* in; u16* out; int k;
  if (i < N4X)            { in = x;  out = xo;  k = i; }
  else if (i < N4X + N4Q) { in = wq; out = wqo; k = i - N4X; }
  else if (i < N4X + N4Q + N4P) { in = wp; out = wpo; k = i - N4X - N4Q; }
  else return;
  float4 v = ((const float4*)in)[k];
  ushort4 o;
  o.x = f2bf(v.x); o.y = f2bf(v.y); o.z = f2bf(v.z); o.w = f2bf(v.w);
  ((ushort4*)out)[k] = o;
}

// ---------------- RoPE sin/cos table [T][32] ----------------
__global__ void rope_table(float* __restrict__ sT, float* __restrict__ cT) {
  int i = blockIdx.x * 256 + threadIdx.x;   // t*32 + j
  int t = i >> 5, j = i & 31;
  float inv = exp2f((float)j * (-13.287712379549449f / 32.0f)); // 10000^(-j/32)
  float ang = (float)t * inv;
  sT[i] = sinf(ang);
  cT[i] = cosf(ang);
}

// ---------------- gemm1 + fused RoPE/head-split epilogue ---------------------
// C = x[4096,1024] * Wqkv[3072,1024]^T. Tile 128x128, 8 waves (4x2), 512 thr.
// T2 XOR-swizzle on LDS tiles via pre-swizzled GLL source; 2D-chunked XCD map.
__global__ __launch_bounds__(512) void gemm_qkv(const u16* __restrict__ A,
                                                const u16* __restrict__ B,
                                                const float* __restrict__ sT,
                                                const float* __restrict__ cT,
                                                u16* __restrict__ Qo,
                                                u16* __restrict__ Ko,
                                                u16* __restrict__ Vo)
{
  const int K = DM;
  __shared__ __align__(16) u16 As[2][128 * 32];
  __shared__ __align__(16) u16 Bs[2][128 * 32];
  const int tid  = threadIdx.x;
  const int wave = tid >> 6, lane = tid & 63;
  const int l15  = lane & 15, lh = lane >> 4;
  const int wr   = wave >> 1, wc = wave & 1;          // 4x2: 32-row x 64-col waves

  int lin = blockIdx.y * gridDim.x + blockIdx.x;      // 0..767
  const int xcd = lin & 7, idx = lin >> 3;            // 96 tiles per XCD
  const size_t bm = (size_t)((xcd & 3) * 8 + idx / 12);    // 0..31
  const size_t bn = (size_t)((xcd >> 2) * 12 + idx % 12);  // 0..23

  f32x4 acc[2][4] = {};

  const u16* Ab = A + bm * 128 * (size_t)K;
  const u16* Bb = B + bn * 128 * (size_t)K;

  const int ea = tid * 8, ra = ea >> 5;
  const int cs = (((tid & 3) ^ (ra & 3)) << 3);       // pre-swizzled source col
  const int xo = ((lh ^ (l15 & 3)) << 3);             // read-side swizzle

  // prologue: stage k=0 into buf 0
  GLL16(Ab + (size_t)ra * K + cs, &As[0][ea]);
  GLL16(Bb + (size_t)ra * K + cs, &Bs[0][ea]);
  asm volatile("s_waitcnt vmcnt(0)" ::: "memory");
  __syncthreads();

  int cur = 0;
  for (int k0 = 0; k0 < K; k0 += 32, cur ^= 1) {
    if (k0 + 32 < K) {
      const int kn = k0 + 32;
      GLL16(Ab + (size_t)ra * K + kn + cs, &As[cur ^ 1][ea]);
      GLL16(Bb + (size_t)ra * K + kn + cs, &Bs[cur ^ 1][ea]);
    }

    bf16x8 af[2], bfr[4];
#pragma unroll
    for (int m = 0; m < 2; ++m)
      af[m] = *(const bf16x8*)(&As[cur][(wr * 32 + m * 16 + l15) * 32 + xo]);
#pragma unroll
    for (int n = 0; n < 4; ++n)
      bfr[n] = *(const bf16x8*)(&Bs[cur][(wc * 64 + n * 16 + l15) * 32 + xo]);
    __builtin_amdgcn_s_setprio(1);
#pragma unroll
    for (int m = 0; m < 2; ++m)
#pragma unroll
      for (int n = 0; n < 4; ++n)
        acc[m][n] = __builtin_amdgcn_mfma_f32_16x16x32_bf16(af[m], bfr[n], acc[m][n], 0, 0, 0);
    __builtin_amdgcn_s_setprio(0);

    asm volatile("s_waitcnt vmcnt(0)" ::: "memory");
    __syncthreads();
  }

  // ---- fused epilogue: RoPE + scatter into fragment layouts ----
  const float QSC = 0.125f * 1.4426950408889634f;    // 1/sqrt(64) * log2(e)
  const int gcb = (int)(bn * 128) + wc * 64;         // wave col base (64-aligned)
  const int rg  = gcb >> 10;                         // 0=Q, 1=K, 2=V
  const int hh2 = (gcb >> 6) & 15;                   // head
  const size_t hb = (size_t)hh2 * 128;

  if (rg < 2) {
    u16* dst = rg ? Ko : Qo;
    const float sc = rg ? 1.f : QSC;
#pragma unroll
    for (int m = 0; m < 2; ++m)
#pragma unroll
      for (int r = 0; r < 4; ++r) {
        int t = (int)(bm * 128) + wr * 32 + m * 16 + lh * 4 + r;
        size_t tb = (hb + (t >> 5)) * 2048 + (size_t)(t & 31) * 8;
#pragma unroll
        for (int n = 0; n < 2; ++n) {
          int d  = n * 16 + l15;                      // < 32
          int d2 = d + 32;
          float s = sT[t * 32 + d], c = cT[t * 32 + d];
          float v1 = acc[m][n][r], v2 = acc[m][n + 2][r];
          dst[tb + (d  >> 4) * 512 + ((d  >> 3) & 1) * 256 + (d  & 7)] =
              f2bf((v1 * c - v2 * s) * sc);
          dst[tb + (d2 >> 4) * 512 + ((d2 >> 3) & 1) * 256 + (d2 & 7)] =
              f2bf((v2 * c + v1 * s) * sc);
        }
      }
  } else {
#pragma unroll
    for (int m = 0; m < 2; ++m)
#pragma unroll
      for (int r = 0; r < 4; ++r) {
        int t = (int)(bm * 128) + wr * 32 + m * 16 + lh * 4 + r;
        size_t tb = (hb + (t >> 5)) * 2048 + (size_t)((t >> 4) & 1) * 512 +
                    ((t >> 3) & 1) * 256 + (t & 7);
#pragma unroll
        for (int n = 0; n < 4; ++n) {
          int d = n * 16 + l15;
          Vo[tb + (size_t)(d >> 5) * 1024 + (size_t)(d & 31) * 8] = f2bf(acc[m][n][r]);
        }
      }
  }
}

// ---------------- GEMM C[M,N] = A[M,K]*B[N,K]^T (proj, fp32 out) ------------
// Tile 64x64, 4 waves (2x2), grid 1024 blocks; T2 XOR-swizzle as in gemm_qkv.
__global__ __launch_bounds__(256) void gemm_proj(const u16* __restrict__ A,
                                                 const u16* __restrict__ B,
                                                 float* __restrict__ Cout,
                                                 int M, int N, int K)
{
  __shared__ __align__(16) u16 As[2][64 * 32];
  __shared__ __align__(16) u16 Bs[2][64 * 32];
  const int tid  = threadIdx.x;
  const int wave = tid >> 6, lane = tid & 63;
  const int l15  = lane & 15, lh = lane >> 4;
  const int wr   = wave >> 1, wc = wave & 1;

  int lin = blockIdx.y * gridDim.x + blockIdx.x;      // 0..1023
  const int xcd = lin & 7, idx = lin >> 3;            // 128 tiles per XCD
  const size_t bm = (size_t)((xcd & 3) * 16 + idx / 8);   // 0..63
  const size_t bn = (size_t)((xcd >> 2) * 8 + idx % 8);   // 0..15

  f32x4 acc[2][2] = {};

  const u16* Ab = A + bm * 64 * (size_t)K;
  const u16* Bb = B + bn * 64 * (size_t)K;

  const int ea = wave * 512 + lane * 8, ra = ea >> 5;
  const int cs = (((lane & 3) ^ (ra & 3)) << 3);      // pre-swizzled source col
  const int xo = ((lh ^ (l15 & 3)) << 3);             // read-side swizzle

  GLL16(Ab + (size_t)ra * K + cs, &As[0][wave * 512]);
  GLL16(Bb + (size_t)ra * K + cs, &Bs[0][wave * 512]);
  asm volatile("s_waitcnt vmcnt(0)" ::: "memory");
  __syncthreads();

  int cur = 0;
  for (int k0 = 0; k0 < K; k0 += 32, cur ^= 1) {
    if (k0 + 32 < K) {
      const int kn = k0 + 32;
      GLL16(Ab + (size_t)ra * K + kn + cs, &As[cur ^ 1][wave * 512]);
      GLL16(Bb + (size_t)ra * K + kn + cs, &Bs[cur ^ 1][wave * 512]);
    }

    bf16x8 af[2], bfr[2];
#pragma unroll
    for (int m = 0; m < 2; ++m)
      af[m] = *(const bf16x8*)(&As[cur][(wr * 32 + m * 16 + l15) * 32 + xo]);
#pragma unroll
    for (int n = 0; n < 2; ++n)
      bfr[n] = *(const bf16x8*)(&Bs[cur][(wc * 32 + n * 16 + l15) * 32 + xo]);
    __builtin_amdgcn_s_setprio(1);
#pragma unroll
    for (int m = 0; m < 2; ++m)
#pragma unroll
      for (int n = 0; n < 2; ++n)
        acc[m][n] = __builtin_amdgcn_mfma_f32_16x16x32_bf16(af[m], bfr[n], acc[m][n], 0, 0, 0);
    __builtin_amdgcn_s_setprio(0);

    asm volatile("s_waitcnt vmcnt(0)" ::: "memory");
    __syncthreads();
  }

#pragma unroll
  for (int m = 0; m < 2; ++m)
#pragma unroll
    for (int n = 0; n < 2; ++n)
#pragma unroll
      for (int r = 0; r < 4; ++r) {
        size_t row = bm * 64 + wr * 32 + m * 16 + lh * 4 + r;
        size_t col = bn * 64 + wc * 32 + n * 16 + l15;
        Cout[row * N + col] = acc[m][n][r];
      }
}

// ---------------- causal flash attention: one (h, qt, g) per block ----------
// grid 16h x 32qt x 4g = 2048 blocks (8/CU residency cap), big-qt first.
// Block: q-tile 128 rows (4 waves x 32), group g = exactly qt+1 kv tiles.
// 16KB LDS (K/V dbuf; P in registers via cvt_pk+permlane). R20-proven body.
__global__ __launch_bounds__(256, 4) void fattn(const u16* __restrict__ Qf,
                                                const u16* __restrict__ Kf,
                                                const u16* __restrict__ Vf,
                                                u16* __restrict__ Op0,
                                                u16* __restrict__ Op123,
                                                float2* __restrict__ lmb)
{
  __shared__ __align__(16) u16 smem[8192];   // [0,4096): K dbuf; [4096,8192): V dbuf

  const int bid = blockIdx.x;
  const int h   = bid & (NH - 1);
  const int g   = (bid >> 4) & 3;            // kv group
  const int qt  = 31 - (bid >> 6);           // big q-tiles dispatched first
  const int tid = threadIdx.x;
  const int wave = tid >> 6, lane = tid & 63;
  const int l31 = lane & 31, hh = lane >> 5;
  const int lb  = lane * 8;                  // linear fragment offset (elems)

  const size_t hbase = (size_t)h * (TSEQ * HD);
  const u16* kg = Kf + hbase;
  const u16* vg = Vf + hbase;
  u16* const Og = g ? (Op123 + (size_t)(g - 1) * (TSEQ * DM)) : Op0;

  const int q0  = qt * 128;
  const int per = qt + 1;                    // 32-kv tiles per group (exact)
  const int kt0 = g * per, kt1 = kt0 + per;
  const int qw0 = q0 + wave * 32;            // this wave's first q row
  const int qgl = qw0 + l31;                 // this lane's q row (global)

  f32x16 oacc0 = {}, oacc1 = {};
  float mrun = 0.f, lrunp = 0.f;             // LANE-PARTIAL l

  // Q fragments (B-operand), 4 k-chunks of 16 d
  bf16x8 qf[4];
  {
    const u16* qp = Qf + hbase + (size_t)(qt * 4 + wave) * 2048;
#pragma unroll
    for (int kc = 0; kc < 4; ++kc)
      qf[kc] = *(const bf16x8*)(qp + kc * 512 + lb);
  }

  // prologue: stage tile kt0 -> buf 0
  GLL16(kg + (size_t)kt0 * 2048 + tid * 8, smem + tid * 8);
  GLL16(vg + (size_t)kt0 * 2048 + tid * 8, smem + 4096 + tid * 8);
  asm volatile("s_waitcnt vmcnt(0)" ::: "memory");
  __syncthreads();

  for (int kt = kt0; kt < kt1; ++kt) {
    const int cur = (kt - kt0) & 1;
    if (kt + 1 < kt1) {                      // stage next tile during compute
      GLL16(kg + (size_t)(kt + 1) * 2048 + tid * 8, smem + (cur ^ 1) * 2048 + tid * 8);
      GLL16(vg + (size_t)(kt + 1) * 2048 + tid * 8, smem + 4096 + (cur ^ 1) * 2048 + tid * 8);
    }
    const u16* kb = smem + cur * 2048;
    const u16* vb = smem + 4096 + cur * 2048;
    const int kv0 = kt * 32;

    // ---- S^T = mfma(K,Q), C-init = -mrun (kt>kt0): exp input ready
    const float mz = (kt == kt0) ? 0.f : -mrun;
    f32x16 s0;
    __builtin_amdgcn_s_setprio(1);
    {
      f32x16 z;
#pragma unroll
      for (int i2 = 0; i2 < 16; ++i2) z[i2] = mz;
      bf16x8 kf0 = *(const bf16x8*)(kb + lb);
      s0 = __builtin_amdgcn_mfma_f32_32x32x16_bf16(kf0, qf[0], z, 0, 0, 0);
    }
#pragma unroll
    for (int kc = 1; kc < 4; ++kc) {
      bf16x8 kf = *(const bf16x8*)(kb + kc * 512 + lb);
      s0 = __builtin_amdgcn_mfma_f32_32x32x16_bf16(kf, qf[kc], s0, 0, 0, 0);
    }
    __builtin_amdgcn_s_setprio(0);

    if (kv0 + 31 > qw0) {                    // wave-uniform: diagonal-ish tile
#pragma unroll
      for (int r = 0; r < 16; ++r) {
        int kvr = kv0 + (r & 3) + 8 * (r >> 2) + 4 * hh;
        if (kvr > qgl) s0[r] = -3.0e38f;
      }
    }

    if (kt == kt0) {                         // group-first tile: row max bias
      float tm = -3.0e38f;
#pragma unroll
      for (int r = 0; r < 16; ++r) tm = fmaxf(tm, s0[r]);
      tm = fmaxf(tm, __shfl_xor(tm, 32));
      mrun = tm;
#pragma unroll
      for (int r = 0; r < 16; ++r) s0[r] -= mrun;     // -3e38-(-3e38)=0 ok
    }

    // ---- exp + lane-partial sum (no cross-lane ops)
    float rs = 0.f;
#pragma unroll
    for (int r = 0; r < 16; ++r) {
      s0[r] = fexp2(s0[r]);
      rs += s0[r];
    }
    lrunp += rs;

    // ---- P fragments in-register: cvt_pk pairs + permlane32_swap
    bf16x8 pf[2];
#pragma unroll
    for (int kc = 0; kc < 2; ++kc) {
      const int e = 8 * kc;
      u32 Xa = cvt_pk_bf16(s0[e + 0], s0[e + 1]);
      u32 Xb = cvt_pk_bf16(s0[e + 2], s0[e + 3]);
      u32 Ya = cvt_pk_bf16(s0[e + 4], s0[e + 5]);
      u32 Yb = cvt_pk_bf16(s0[e + 6], s0[e + 7]);
      asm volatile("v_permlane32_swap_b32 %0, %1" : "+v"(Xa), "+v"(Ya));
      asm volatile("v_permlane32_swap_b32 %0, %1" : "+v"(Xb), "+v"(Yb));
      union { u32 u[4]; bf16x8 v; } pu;
      pu.u[0] = Xa; pu.u[1] = Xb; pu.u[2] = Ya; pu.u[3] = Yb;
      pf[kc] = pu.v;
    }

    // ---- PV: O^T += V * P   (oacc_m: d = m*32 + rowmap, q = l31)
    __builtin_amdgcn_s_setprio(1);
#pragma unroll
    for (int s2 = 0; s2 < 2; ++s2) {
      bf16x8 v0 = *(const bf16x8*)(vb + (0 * 2 + s2) * 512 + lb);
      bf16x8 v1 = *(const bf16x8*)(vb + (1 * 2 + s2) * 512 + lb);
      oacc0 = __builtin_amdgcn_mfma_f32_32x32x16_bf16(v0, pf[s2], oacc0, 0, 0, 0);
      oacc1 = __builtin_amdgcn_mfma_f32_32x32x16_bf16(v1, pf[s2], oacc1, 0, 0, 0);
    }
    __builtin_amdgcn_s_setprio(0);

    asm volatile("s_waitcnt vmcnt(0)" ::: "memory");
    __syncthreads();
  }

  // ---- epilogue: reduce lane-partial l, normalize, LDS bounce, store -----
  {
    float lr = lrunp + __shfl_xor(lrunp, 32);
    float inv = 1.f / lr;
    u16* scr = smem + wave * 2048;           // wave-private 4KB (K/V bufs done)
#pragma unroll
    for (int dt = 0; dt < 2; ++dt)
#pragma unroll
      for (int rq = 0; rq < 4; ++rq) {
        float v0 = (dt ? oacc1[4 * rq + 0] : oacc0[4 * rq + 0]) * inv;
        float v1 = (dt ? oacc1[4 * rq + 1] : oacc0[4 * rq + 1]) * inv;
        float v2 = (dt ? oacc1[4 * rq + 2] : oacc0[4 * rq + 2]) * inv;
        float v3 = (dt ? oacc1[4 * rq + 3] : oacc0[4 * rq + 3]) * inv;
        uint2 wv;
        wv.x = cvt_pk_bf16(v0, v1);
        wv.y = cvt_pk_bf16(v2, v3);
        int g2 = 4 * dt + rq;
        *(uint2*)(scr + l31 * 64 + ((g2 ^ (l31 & 7)) * 8) + 4 * hh) = wv;
      }
    asm volatile("s_waitcnt lgkmcnt(0)" ::: "memory");
    __builtin_amdgcn_sched_barrier(0);
    const int q  = lane >> 1;                // 32 rows x 2 d-halves
    const int dh = lane & 1;
#pragma unroll
    for (int c2 = 0; c2 < 4; ++c2) {
      int gg = dh * 4 + c2;
      i32x4 v = *(const i32x4*)(scr + q * 64 + ((gg ^ (q & 7)) * 8));
      *(i32x4*)(Og + (size_t)(qw0 + q) * DM + h * HD + dh * 32 + c2 * 8) = v;
    }
    if (hh == 0)                             // per-q stats (m log2-domain, l)
      lmb[((size_t)g * NH + h) * TSEQ + qgl] = make_float2(mrun, lr);
  }
}

// ---------------- merge the four kv-group partials ----------------
// O[q][h*64+d] = sum_g a_g * O_g,  a_g = 2^(m_g - m) * l_g / sum
__global__ void merge_o(const u16* __restrict__ Op0, const u16* __restrict__ Op123,
                        const float2* __restrict__ lmb, u16* __restrict__ Ob) {
  int i = blockIdx.x * 256 + threadIdx.x;    // [0, TSEQ*DM/8)
  int q  = i >> 7;
  int c8 = (i & 127) * 8;
  int h  = c8 >> 6;
  float2 s0 = lmb[(size_t)h * TSEQ + q];
  float2 s1 = lmb[((size_t)NH + h) * TSEQ + q];
  float2 s2 = lmb[((size_t)2 * NH + h) * TSEQ + q];
  float2 s3 = lmb[((size_t)3 * NH + h) * TSEQ + q];
  float m  = fmaxf(fmaxf(s0.x, s1.x), fmaxf(s2.x, s3.x));
  float w0 = fexp2(s0.x - m) * s0.y;
  float w1 = fexp2(s1.x - m) * s1.y;
  float w2 = fexp2(s2.x - m) * s2.y;
  float w3 = fexp2(s3.x - m) * s3.y;
  float inv = 1.f / (w0 + w1 + w2 + w3);
  float a0 = w0 * inv, a1 = w1 * inv, a2 = w2 * inv, a3 = w3 * inv;
  size_t off = (size_t)q * DM + c8;
  i32x4 u0 = *(const i32x4*)(Op0 + off);
  i32x4 u1 = *(const i32x4*)(Op123 + off);
  i32x4 u2 = *(const i32x4*)(Op123 + (size_t)(TSEQ * DM) + off);
  i32x4 u3 = *(const i32x4*)(Op123 + 2 * (size_t)(TSEQ * DM) + off);
  const u16* p0 = (const u16*)&u0;
  const u16* p1 = (const u16*)&u1;
  const u16* p2 = (const u16*)&u2;
  const u16* p3 = (const u16*)&u3;
  union { u16 o[8]; i32x4 v; } r;
#pragma unroll
  for (int e = 0; e < 8; ++e)
    r.o[e] = f2bf(a0 * bf2f(p0[e]) + a1 * bf2f(p1[e]) +
                  a2 * bf2f(p2[e]) + a3 * bf2f(p3[e]));
  *(i32x4*)(Ob + off) = r.v;
}

extern "C" void kernel_launch(void* const* d_in, const int* in_sizes, int n_in,
                              void* d_out, int out_size, void* d_ws, size_t ws_size,
                              hipStream_t stream)
{
  const float* x     = (const float*)d_in[0];
  const float* wqkv  = (const float*)d_in[1];
  const float* wproj = (const float*)d_in[2];
  float* out = (float*)d_out;

  char* ws = (char*)d_ws;
  size_t off = 0;
  u16* xb   = (u16*)(ws + off); off += (size_t)TSEQ * DM * 2;
  u16* wqb  = (u16*)(ws + off); off += (size_t)NQKV * DM * 2;
  u16* wpb  = (u16*)(ws + off); off += (size_t)DM * DM * 2;
  u16* qkvb = (u16*)(ws + off); off += (size_t)TSEQ * NQKV * 2;   // scratch (partials)
  u16* Qb   = (u16*)(ws + off); off += (size_t)NH * TSEQ * HD * 2;
  u16* Kb   = (u16*)(ws + off); off += (size_t)NH * TSEQ * HD * 2;
  u16* Vb   = (u16*)(ws + off); off += (size_t)NH * TSEQ * HD * 2;
  u16* Ob   = (u16*)(ws + off); off += (size_t)TSEQ * DM * 2;
  float* sT = (float*)(ws + off); off += (size_t)TSEQ * 32 * 4;
  float* cT = (float*)(ws + off); off += (size_t)TSEQ * 32 * 4;

  // kv-split partials: g0 writes Ob directly; g1-3 alias qkvb (24MB scratch);
  // stats alias wqb (dead after gemm_qkv).
  u16*    Op123 = qkvb;
  float2* lmb   = (float2*)wqb;

  const int ncast = N4X + N4Q + N4P;
  cast3_kernel<<<(ncast + 255) / 256, 256, 0, stream>>>(x, xb, wqkv, wqb, wproj, wpb);
  rope_table<<<(TSEQ * 32) / 256, 256, 0, stream>>>(sT, cT);

  gemm_qkv<<<dim3(NQKV / 128, TSEQ / 128), 512, 0, stream>>>(xb, wqb, sT, cT, Qb, Kb, Vb);

  fattn<<<NH * 32 * 4, 256, 0, stream>>>(Qb, Kb, Vb, Ob, Op123, lmb);

  merge_o<<<(TSEQ * DM / 8) / 256, 256, 0, stream>>>(Ob, Op123, lmb, Ob);

  gemm_proj<<<dim3(DM / 64, TSEQ / 64), 256, 0, stream>>>(Ob, wpb, out, TSEQ, DM, DM);
}